// Round 1
// baseline (521.866 us; speedup 1.0000x reference)
//
#include <hip/hip_runtime.h>
#include <hip/hip_bf16.h>

typedef short bf16x8 __attribute__((ext_vector_type(8)));
typedef float f32x4 __attribute__((ext_vector_type(4)));

#define DEVI __device__ __forceinline__

DEVI unsigned short f2b(float x) {
  __hip_bfloat16 h = __float2bfloat16(x);
  return *reinterpret_cast<unsigned short*>(&h);
}

DEVI void load_lds16(const void* g, void* l) {
  __builtin_amdgcn_global_load_lds(
      (__attribute__((address_space(1))) void*)(void*)g,
      (__attribute__((address_space(3))) void*)l, 16, 0, 0);
}

// C = A(MxK, lda) * Bw(NxK, ldb)^T  -- 128x128 tile, BK=32, 256 threads, 4 waves.
// EPI: 0 new_hidden (f32 + bf16), 1 mid (relu->bf16, bias guarded by bias_n),
//      2 out (f32), 3 h_proj (f32), 4 lc (+addmat+bias2 -> bf16), 5 cell (tanh->f32)
template<int EPI>
__global__ __launch_bounds__(256, 2)
void gemm_bt(const unsigned short* __restrict__ A, int lda,
             const unsigned short* __restrict__ Bw, int ldb,
             int N, int K,
             const float* __restrict__ bias1, int bias_n,
             const float* __restrict__ addmat,
             const float* __restrict__ bias2,
             float* __restrict__ outf,
             unsigned short* __restrict__ outb)
{
  __shared__ unsigned short As[128 * 32];
  __shared__ unsigned short Bs[128 * 32];

  const int tid = threadIdx.x;
  const int w   = tid >> 6;
  const int l   = tid & 63;
  const int wr  = w >> 1, wc = w & 1;   // 2x2 wave grid, 64x64 per wave
  const int lr  = l & 15, kg = l >> 4;  // fragment row, k-group

  const int m0 = blockIdx.y * 128;
  const int n0 = blockIdx.x * 128;

  // staging: 8 chunks of 16 rows (1 KiB each); wave w stages chunks 2w, 2w+1
  const int c0   = w * 2;
  const int srow = l >> 2;        // row within chunk
  const int skb  = (l & 3) * 8;   // k-element offset (8 bf16 = 16 B)

  f32x4 acc[4][4];
#pragma unroll
  for (int m = 0; m < 4; ++m)
#pragma unroll
    for (int n = 0; n < 4; ++n) acc[m][n] = (f32x4)0.f;

  for (int k0 = 0; k0 < K; k0 += 32) {
    __syncthreads();  // previous compute done before overwriting LDS
#pragma unroll
    for (int i = 0; i < 2; ++i) {
      const int c = c0 + i;
      const int row = c * 16 + srow;
      load_lds16(A  + (long)(m0 + row) * lda + (k0 + skb), &As[c * 512]);
      load_lds16(Bw + (long)(n0 + row) * ldb + (k0 + skb), &Bs[c * 512]);
    }
    __syncthreads();  // vmcnt(0) drained by compiler before barrier

    bf16x8 af[4], bfr[4];
#pragma unroll
    for (int m = 0; m < 4; ++m)
      af[m] = *reinterpret_cast<const bf16x8*>(&As[(wr * 64 + m * 16 + lr) * 32 + kg * 8]);
#pragma unroll
    for (int n = 0; n < 4; ++n)
      bfr[n] = *reinterpret_cast<const bf16x8*>(&Bs[(wc * 64 + n * 16 + lr) * 32 + kg * 8]);
#pragma unroll
    for (int m = 0; m < 4; ++m)
#pragma unroll
      for (int n = 0; n < 4; ++n)
        acc[m][n] = __builtin_amdgcn_mfma_f32_16x16x32_bf16(af[m], bfr[n], acc[m][n], 0, 0, 0);
  }

  // epilogue: C row = m0 + wr*64 + m*16 + kg*4 + j, col = n0 + wc*64 + n*16 + lr
#pragma unroll
  for (int m = 0; m < 4; ++m) {
    const int r0 = m0 + wr * 64 + m * 16 + kg * 4;
#pragma unroll
    for (int n = 0; n < 4; ++n) {
      const int gc = n0 + wc * 64 + n * 16 + lr;
      float b1;
      if (EPI == 1) b1 = (gc < bias_n) ? bias1[gc] : 0.0f;
      else          b1 = bias1[gc];
#pragma unroll
      for (int j = 0; j < 4; ++j) {
        const long idx = (long)(r0 + j) * N + gc;
        float v = acc[m][n][j] + b1;
        if (EPI == 0)      { outf[idx] = v; outb[idx] = f2b(v); }
        else if (EPI == 1) { outb[idx] = f2b(v > 0.f ? v : 0.f); }
        else if (EPI == 2 || EPI == 3) { outf[idx] = v; }
        else if (EPI == 4) { v += addmat[idx] + bias2[gc]; outb[idx] = f2b(v); }
        else               { outf[idx] = tanhf(v); }
      }
    }
  }
}

// fp32 -> bf16, 4 elems/thread, optional strided destination rows
__global__ void cvt4(const float* __restrict__ src, unsigned short* __restrict__ dst,
                     long n4, int cols4, int ldd)
{
  const bool contig = (ldd == cols4 * 4);
  for (long i = blockIdx.x * (long)blockDim.x + threadIdx.x; i < n4;
       i += (long)gridDim.x * blockDim.x) {
    float4 v = reinterpret_cast<const float4*>(src)[i];
    ushort4 o;
    o.x = f2b(v.x); o.y = f2b(v.y); o.z = f2b(v.z); o.w = f2b(v.w);
    long idx;
    if (contig) idx = i * 4;
    else { long r = i / cols4; long c = i - r * cols4; idx = r * (long)ldd + c * 4; }
    *reinterpret_cast<ushort4*>(&dst[idx]) = o;
  }
}

// W_mo [256][100] fp32 -> [256][128] bf16 (cols 100..127 pre-zeroed by memset)
__global__ void cvt_wmo(const float* __restrict__ src, unsigned short* __restrict__ dst)
{
  int i = blockIdx.x * blockDim.x + threadIdx.x;
  if (i < 256 * 100) {
    int r = i / 100, c = i - r * 100;
    dst[r * 128 + c] = f2b(src[i]);
  }
}

extern "C" void kernel_launch(void* const* d_in, const int* in_sizes, int n_in,
                              void* d_out, int out_size, void* d_ws, size_t ws_size,
                              hipStream_t stream) {
  const int B = 4096, I = 1024, H = 2048, O = 256;
  const int K1 = I + 3 * H;  // 7168

  const float* x_in  = (const float*)d_in[0];
  const float* x_hid = (const float*)d_in[1];
  const float* x_ph  = (const float*)d_in[2];
  const float* x_cel = (const float*)d_in[3];
  const float* Wch2  = (const float*)d_in[4];
  const float* bch2  = (const float*)d_in[5];
  const float* Wcm2  = (const float*)d_in[6];
  const float* bcm2  = (const float*)d_in[7];
  const float* Wmo   = (const float*)d_in[8];
  const float* bmo   = (const float*)d_in[9];
  const float* Wci   = (const float*)d_in[10];
  const float* bci   = (const float*)d_in[11];
  const float* Wch   = (const float*)d_in[12];
  const float* bch   = (const float*)d_in[13];
  const float* Wfc   = (const float*)d_in[14];
  const float* bfc   = (const float*)d_in[15];
  const float* bias  = (const float*)d_in[16];

  float* out_out  = (float*)d_out;                 // [B,O]
  float* out_nh   = out_out + (long)B * O;         // [B,H]
  float* out_cell = out_nh + (long)B * H;          // [B,H]
  float* out_ph   = out_cell + (long)B * H;        // [B,H]

  char* p = (char*)d_ws;
  unsigned short* cmb   = (unsigned short*)p; p += (long)B * K1 * 2;    // combined bf16
  unsigned short* wch2b = (unsigned short*)p; p += (long)H * K1 * 2;
  unsigned short* wcm2b = (unsigned short*)p; p += (long)128 * K1 * 2;  // padded to 128 rows
  unsigned short* wmob  = (unsigned short*)p; p += (long)O * 128 * 2;   // padded K->128
  unsigned short* wcib  = (unsigned short*)p; p += (long)H * I * 2;
  unsigned short* wchb  = (unsigned short*)p; p += (long)H * H * 2;
  unsigned short* wfcb  = (unsigned short*)p; p += (long)H * H * 2;
  unsigned short* nhb   = (unsigned short*)p; p += (long)B * H * 2;     // new_hidden bf16
  unsigned short* midb  = (unsigned short*)p; p += (long)B * 128 * 2;   // mid padded
  unsigned short* lcb   = (unsigned short*)p; p += (long)B * H * 2;     // lc bf16

  const dim3 cb(256);

  // ---- conversions ----
  cvt4<<<1024, cb, 0, stream>>>(x_in,  cmb,        (long)B * I / 4, I / 4, K1);
  cvt4<<<1024, cb, 0, stream>>>(x_hid, cmb + 1024, (long)B * H / 4, H / 4, K1);
  cvt4<<<1024, cb, 0, stream>>>(x_ph,  cmb + 3072, (long)B * H / 4, H / 4, K1);
  cvt4<<<1024, cb, 0, stream>>>(x_cel, cmb + 5120, (long)B * H / 4, H / 4, K1);
  cvt4<<<1024, cb, 0, stream>>>(Wch2, wch2b, (long)H * K1 / 4, K1 / 4, K1);
  cvt4<<<256,  cb, 0, stream>>>(Wcm2, wcm2b, (long)100 * K1 / 4, K1 / 4, K1);
  hipMemsetAsync(wcm2b + (long)100 * K1, 0, (long)28 * K1 * 2, stream);  // pad rows
  hipMemsetAsync(wmob, 0, (long)O * 128 * 2, stream);
  cvt_wmo<<<100, cb, 0, stream>>>(Wmo, wmob);
  cvt4<<<512,  cb, 0, stream>>>(Wci, wcib, (long)H * I / 4, I / 4, I);
  cvt4<<<1024, cb, 0, stream>>>(Wch, wchb, (long)H * H / 4, H / 4, H);
  cvt4<<<1024, cb, 0, stream>>>(Wfc, wfcb, (long)H * H / 4, H / 4, H);

  // ---- GEMM chain ----
  // 1) new_hidden = combined @ W_ch2^T + b_ch2   (f32 out + bf16 stage)
  gemm_bt<0><<<dim3(H / 128, B / 128), cb, 0, stream>>>(
      cmb, K1, wch2b, K1, H, K1, bch2, H, nullptr, nullptr, out_nh, nhb);
  // 2) mid = relu(combined @ W_cm2^T + b_cm2)  (padded N=128)
  gemm_bt<1><<<dim3(1, B / 128), cb, 0, stream>>>(
      cmb, K1, wcm2b, K1, 128, K1, bcm2, 100, nullptr, nullptr, nullptr, midb);
  // 3) out = mid @ W_mo^T + b_mo   (K padded to 128)
  gemm_bt<2><<<dim3(O / 128, B / 128), cb, 0, stream>>>(
      midb, 128, wmob, 128, O, 128, bmo, O, nullptr, nullptr, out_out, nullptr);
  // 4) h_proj = new_hidden @ W_ch^T + b_ch  -> new_prev_hidden (f32)
  gemm_bt<3><<<dim3(H / 128, B / 128), cb, 0, stream>>>(
      nhb, H, wchb, H, H, H, bch, H, nullptr, nullptr, out_ph, nullptr);
  // 5) lc = input @ W_ci^T + b_ci + h_proj + bias  (bf16 stage)
  gemm_bt<4><<<dim3(H / 128, B / 128), cb, 0, stream>>>(
      cmb, K1, wcib, I, H, I, bci, H, out_ph, bias, nullptr, lcb);
  // 6) new_cell = tanh(lc @ W_fc^T + b_fc)  (f32)
  gemm_bt<5><<<dim3(H / 128, B / 128), cb, 0, stream>>>(
      lcb, H, wfcb, H, H, H, bfc, H, nullptr, nullptr, out_cell, nullptr);

  (void)in_sizes; (void)n_in; (void)out_size; (void)ws_size;
}

// Round 2
// 442.682 us; speedup vs baseline: 1.1789x; 1.1789x over previous
//
#include <hip/hip_runtime.h>
#include <hip/hip_bf16.h>
#include <math.h>

typedef short bf16x8 __attribute__((ext_vector_type(8)));
typedef float f32x4 __attribute__((ext_vector_type(4)));
typedef unsigned short u16;
typedef unsigned short u16x8v __attribute__((ext_vector_type(8)));

#define DEVI __device__ __forceinline__

DEVI u16 f2b(float x) {
  __hip_bfloat16 h = __float2bfloat16(x);
  return *reinterpret_cast<u16*>(&h);
}

DEVI void load_lds16(const void* g, void* l) {
  __builtin_amdgcn_global_load_lds(
      (__attribute__((address_space(1))) void*)(void*)g,
      (__attribute__((address_space(3))) void*)l, 16, 0, 0);
}

// 128x128 tile, BK=32, 256 thr / 4 waves. LDS XOR-swizzle at 16B granule:
// granule (row,q) lives at linear quad q ^ ((row>>1)&3).  global_load_lds
// writes linearly, so the GLOBAL source column is pre-swizzled per-lane
// (rule #21: linear dest + inverse-swz source + swz on read).
DEVI void gemm_core(const u16* __restrict__ A, int lda,
                    const u16* __restrict__ Bw, int ldb,
                    int K, int m0, int n0,
                    u16* As, u16* Bs, f32x4 (&acc)[4][4])
{
  const int tid = threadIdx.x;
  const int w = tid >> 6, l = tid & 63;
  const int wr = w >> 1, wc = w & 1;
  const int lr = l & 15, kg = l >> 4;
  const int c0 = w * 2;
  const int srow = l >> 2, kq = l & 3;

#pragma unroll
  for (int m = 0; m < 4; ++m)
#pragma unroll
    for (int n = 0; n < 4; ++n) acc[m][n] = (f32x4)0.f;

  int aoff[4], boff[4];
#pragma unroll
  for (int m = 0; m < 4; ++m) {
    int ra = wr * 64 + m * 16 + lr;
    aoff[m] = ra * 32 + ((kg ^ ((ra >> 1) & 3)) << 3);
    int rb = wc * 64 + m * 16 + lr;
    boff[m] = rb * 32 + ((kg ^ ((rb >> 1) & 3)) << 3);
  }

  for (int k0 = 0; k0 < K; k0 += 32) {
    __syncthreads();
#pragma unroll
    for (int i = 0; i < 2; ++i) {
      const int c = c0 + i;
      const int row = c * 16 + srow;
      const int kcol = (kq ^ ((row >> 1) & 3)) << 3;
      load_lds16(A  + (long)(m0 + row) * lda + k0 + kcol, &As[c * 512]);
      load_lds16(Bw + (long)(n0 + row) * ldb + k0 + kcol, &Bs[c * 512]);
    }
    __syncthreads();

    bf16x8 af[4], bfr[4];
#pragma unroll
    for (int m = 0; m < 4; ++m) af[m]  = *reinterpret_cast<const bf16x8*>(&As[aoff[m]]);
#pragma unroll
    for (int n = 0; n < 4; ++n) bfr[n] = *reinterpret_cast<const bf16x8*>(&Bs[boff[n]]);
#pragma unroll
    for (int m = 0; m < 4; ++m)
#pragma unroll
      for (int n = 0; n < 4; ++n)
        acc[m][n] = __builtin_amdgcn_mfma_f32_16x16x32_bf16(af[m], bfr[n], acc[m][n], 0, 0, 0);
  }
}

// Launch A: bx<16 -> G1 new_hidden ; bx==16 -> G2 mid ; bx>=17 -> G5a ci-part
__global__ __launch_bounds__(256, 2)
void gemmA(const u16* __restrict__ cmb,
           const u16* __restrict__ wch2b, const float* __restrict__ bch2,
           const u16* __restrict__ wcm2b, const float* __restrict__ bcm2,
           const u16* __restrict__ wcib,  const float* __restrict__ bci,
           const float* __restrict__ bias,
           float* __restrict__ out_nh, u16* __restrict__ nhb,
           u16* __restrict__ midb, float* __restrict__ cif)
{
  __shared__ u16 As[128 * 32], Bs[128 * 32];
  const int m0 = blockIdx.y * 128;
  const int bx = blockIdx.x;
  const int tid = threadIdx.x;
  const int w = tid >> 6, l = tid & 63;
  const int wr = w >> 1, wc = w & 1;
  const int lr = l & 15, kg = l >> 4;
  f32x4 acc[4][4];

  if (bx < 16) {
    const int n0 = bx * 128;
    gemm_core(cmb, 7168, wch2b, 7168, 7168, m0, n0, As, Bs, acc);
#pragma unroll
    for (int m = 0; m < 4; ++m) {
      const int r0 = m0 + wr * 64 + m * 16 + kg * 4;
#pragma unroll
      for (int n = 0; n < 4; ++n) {
        const int gc = n0 + wc * 64 + n * 16 + lr;
        const float b1 = bch2[gc];
#pragma unroll
        for (int j = 0; j < 4; ++j) {
          const long idx = (long)(r0 + j) * 2048 + gc;
          float v = acc[m][n][j] + b1;
          out_nh[idx] = v; nhb[idx] = f2b(v);
        }
      }
    }
  } else if (bx == 16) {
    gemm_core(cmb, 7168, wcm2b, 7168, 7168, m0, 0, As, Bs, acc);
#pragma unroll
    for (int m = 0; m < 4; ++m) {
      const int r0 = m0 + wr * 64 + m * 16 + kg * 4;
#pragma unroll
      for (int n = 0; n < 4; ++n) {
        const int gc = wc * 64 + n * 16 + lr;
        const float b1 = (gc < 100) ? bcm2[gc] : 0.0f;
#pragma unroll
        for (int j = 0; j < 4; ++j) {
          float v = acc[m][n][j] + b1;
          midb[(long)(r0 + j) * 128 + gc] = f2b(v > 0.f ? v : 0.f);
        }
      }
    }
  } else {
    const int n0 = (bx - 17) * 128;
    gemm_core(cmb, 7168, wcib, 1024, 1024, m0, n0, As, Bs, acc);
#pragma unroll
    for (int m = 0; m < 4; ++m) {
      const int r0 = m0 + wr * 64 + m * 16 + kg * 4;
#pragma unroll
      for (int n = 0; n < 4; ++n) {
        const int gc = n0 + wc * 64 + n * 16 + lr;
        const float b1 = bci[gc] + bias[gc];
#pragma unroll
        for (int j = 0; j < 4; ++j)
          cif[(long)(r0 + j) * 2048 + gc] = acc[m][n][j] + b1;
      }
    }
  }
}

// Launch B: bx<16 -> G4 h_proj (+fused lc) ; bx>=16 -> G3 out
__global__ __launch_bounds__(256, 2)
void gemmB(const u16* __restrict__ nhb, const u16* __restrict__ wchb,
           const float* __restrict__ bch, const float* __restrict__ cif,
           float* __restrict__ out_ph, u16* __restrict__ lcb,
           const u16* __restrict__ midb, const u16* __restrict__ wmob,
           const float* __restrict__ bmo, float* __restrict__ out_out)
{
  __shared__ u16 As[128 * 32], Bs[128 * 32];
  const int m0 = blockIdx.y * 128;
  const int bx = blockIdx.x;
  const int tid = threadIdx.x;
  const int w = tid >> 6, l = tid & 63;
  const int wr = w >> 1, wc = w & 1;
  const int lr = l & 15, kg = l >> 4;
  f32x4 acc[4][4];

  if (bx < 16) {
    const int n0 = bx * 128;
    gemm_core(nhb, 2048, wchb, 2048, 2048, m0, n0, As, Bs, acc);
#pragma unroll
    for (int m = 0; m < 4; ++m) {
      const int r0 = m0 + wr * 64 + m * 16 + kg * 4;
#pragma unroll
      for (int n = 0; n < 4; ++n) {
        const int gc = n0 + wc * 64 + n * 16 + lr;
        const float b1 = bch[gc];
#pragma unroll
        for (int j = 0; j < 4; ++j) {
          const long idx = (long)(r0 + j) * 2048 + gc;
          float v = acc[m][n][j] + b1;       // h_proj
          out_ph[idx] = v;
          lcb[idx] = f2b(v + cif[idx]);      // lc = h_proj + (x@Wci^T + b_ci + bias)
        }
      }
    }
  } else {
    const int n0 = (bx - 16) * 128;
    gemm_core(midb, 128, wmob, 128, 128, m0, n0, As, Bs, acc);
#pragma unroll
    for (int m = 0; m < 4; ++m) {
      const int r0 = m0 + wr * 64 + m * 16 + kg * 4;
#pragma unroll
      for (int n = 0; n < 4; ++n) {
        const int gc = n0 + wc * 64 + n * 16 + lr;
        const float b1 = bmo[gc];
#pragma unroll
        for (int j = 0; j < 4; ++j)
          out_out[(long)(r0 + j) * 256 + gc] = acc[m][n][j] + b1;
      }
    }
  }
}

// Launch D: new_cell = tanh(lc @ W_fc^T + b_fc)
__global__ __launch_bounds__(256, 2)
void gemmD(const u16* __restrict__ lcb, const u16* __restrict__ wfcb,
           const float* __restrict__ bfc, float* __restrict__ out_cell)
{
  __shared__ u16 As[128 * 32], Bs[128 * 32];
  const int m0 = blockIdx.y * 128;
  const int n0 = blockIdx.x * 128;
  const int tid = threadIdx.x;
  const int w = tid >> 6, l = tid & 63;
  const int wr = w >> 1, wc = w & 1;
  const int lr = l & 15, kg = l >> 4;
  f32x4 acc[4][4];

  gemm_core(lcb, 2048, wfcb, 2048, 2048, m0, n0, As, Bs, acc);
#pragma unroll
  for (int m = 0; m < 4; ++m) {
    const int r0 = m0 + wr * 64 + m * 16 + kg * 4;
#pragma unroll
    for (int n = 0; n < 4; ++n) {
      const int gc = n0 + wc * 64 + n * 16 + lr;
      const float b1 = bfc[gc];
#pragma unroll
      for (int j = 0; j < 4; ++j)
        out_cell[(long)(r0 + j) * 2048 + gc] = tanhf(acc[m][n][j] + b1);
    }
  }
}

// combined = [input | hidden | prev_hidden | cell] fp32 -> bf16, 8 elems/thread
__global__ void cvt_in(const float* __restrict__ x_in, const float* __restrict__ x_hid,
                       const float* __restrict__ x_ph, const float* __restrict__ x_cel,
                       u16* __restrict__ cmb)
{
  const long total = (long)4096 * 896;  // 8-elem groups per row: 7168/8 = 896
  for (long i = blockIdx.x * (long)blockDim.x + threadIdx.x; i < total;
       i += (long)gridDim.x * blockDim.x) {
    const int c8 = (int)(i % 896);
    const long row = i / 896;
    const float* src; long sidx;
    if (c8 < 128)      { src = x_in;  sidx = row * 1024 + (long)c8 * 8; }
    else if (c8 < 384) { src = x_hid; sidx = row * 2048 + (long)(c8 - 128) * 8; }
    else if (c8 < 640) { src = x_ph;  sidx = row * 2048 + (long)(c8 - 384) * 8; }
    else               { src = x_cel; sidx = row * 2048 + (long)(c8 - 640) * 8; }
    float4 v0 = *reinterpret_cast<const float4*>(src + sidx);
    float4 v1 = *reinterpret_cast<const float4*>(src + sidx + 4);
    u16x8v o;
    o[0] = f2b(v0.x); o[1] = f2b(v0.y); o[2] = f2b(v0.z); o[3] = f2b(v0.w);
    o[4] = f2b(v1.x); o[5] = f2b(v1.y); o[6] = f2b(v1.z); o[7] = f2b(v1.w);
    *reinterpret_cast<u16x8v*>(&cmb[row * 7168 + (long)c8 * 8]) = o;
  }
}

// 5 contiguous fp32->bf16 weight segments in one kernel
__global__ void cvt_w5(const float* __restrict__ s0, const float* __restrict__ s1,
                       const float* __restrict__ s2, const float* __restrict__ s3,
                       const float* __restrict__ s4,
                       u16* __restrict__ d0, u16* __restrict__ d1, u16* __restrict__ d2,
                       u16* __restrict__ d3, u16* __restrict__ d4,
                       long e0, long e1, long e2, long e3, long e4)
{
  for (long i = blockIdx.x * (long)blockDim.x + threadIdx.x; i < e4;
       i += (long)gridDim.x * blockDim.x) {
    const float* s; u16* d; long j;
    if (i < e0)      { s = s0; d = d0; j = i; }
    else if (i < e1) { s = s1; d = d1; j = i - e0; }
    else if (i < e2) { s = s2; d = d2; j = i - e1; }
    else if (i < e3) { s = s3; d = d3; j = i - e2; }
    else             { s = s4; d = d4; j = i - e3; }
    float4 v = reinterpret_cast<const float4*>(s)[j];
    ushort4 o; o.x = f2b(v.x); o.y = f2b(v.y); o.z = f2b(v.z); o.w = f2b(v.w);
    reinterpret_cast<ushort4*>(d)[j] = o;
  }
}

// W_mo [256][100] fp32 -> [256][128] bf16 (cols 100..127 pre-zeroed by memset)
__global__ void cvt_wmo(const float* __restrict__ src, u16* __restrict__ dst)
{
  int i = blockIdx.x * blockDim.x + threadIdx.x;
  if (i < 256 * 100) {
    int r = i / 100, c = i - r * 100;
    dst[r * 128 + c] = f2b(src[i]);
  }
}

extern "C" void kernel_launch(void* const* d_in, const int* in_sizes, int n_in,
                              void* d_out, int out_size, void* d_ws, size_t ws_size,
                              hipStream_t stream) {
  const int B = 4096, I = 1024, H = 2048, O = 256;
  const int K1 = I + 3 * H;  // 7168

  const float* x_in  = (const float*)d_in[0];
  const float* x_hid = (const float*)d_in[1];
  const float* x_ph  = (const float*)d_in[2];
  const float* x_cel = (const float*)d_in[3];
  const float* Wch2  = (const float*)d_in[4];
  const float* bch2  = (const float*)d_in[5];
  const float* Wcm2  = (const float*)d_in[6];
  const float* bcm2  = (const float*)d_in[7];
  const float* Wmo   = (const float*)d_in[8];
  const float* bmo   = (const float*)d_in[9];
  const float* Wci   = (const float*)d_in[10];
  const float* bci   = (const float*)d_in[11];
  const float* Wch   = (const float*)d_in[12];
  const float* bch   = (const float*)d_in[13];
  const float* Wfc   = (const float*)d_in[14];
  const float* bfc   = (const float*)d_in[15];
  const float* bias  = (const float*)d_in[16];

  float* out_out  = (float*)d_out;                 // [B,O]
  float* out_nh   = out_out + (long)B * O;         // [B,H]
  float* out_cell = out_nh + (long)B * H;          // [B,H]  (doubles as cif scratch)
  float* out_ph   = out_cell + (long)B * H;        // [B,H]

  char* p = (char*)d_ws;
  u16* cmb   = (u16*)p; p += (long)B * K1 * 2;
  u16* wch2b = (u16*)p; p += (long)H * K1 * 2;
  u16* wcm2b = (u16*)p; p += (long)128 * K1 * 2;   // 100 rows + 28 zero-pad rows
  u16* wmob  = (u16*)p; p += (long)O * 128 * 2;    // K padded to 128
  u16* wcib  = (u16*)p; p += (long)H * I * 2;
  u16* wchb  = (u16*)p; p += (long)H * H * 2;
  u16* wfcb  = (u16*)p; p += (long)H * H * 2;
  u16* nhb   = (u16*)p; p += (long)B * H * 2;
  u16* midb  = (u16*)p; p += (long)B * 128 * 2;
  u16* lcb   = (u16*)p; p += (long)B * H * 2;

  const dim3 cb(256);

  // zero wcm2b pad rows + all of wmob in one shot (adjacent in ws)
  hipMemsetAsync(wcm2b + (long)100 * K1, 0, (size_t)(28 * K1 + 256 * 128) * 2, stream);

  cvt_in<<<2048, cb, 0, stream>>>(x_in, x_hid, x_ph, x_cel, cmb);
  {
    long e0 = (long)H * K1 / 4;
    long e1 = e0 + (long)100 * K1 / 4;
    long e2 = e1 + (long)H * I / 4;
    long e3 = e2 + (long)H * H / 4;
    long e4 = e3 + (long)H * H / 4;
    cvt_w5<<<2048, cb, 0, stream>>>(Wch2, Wcm2, Wci, Wch, Wfc,
                                    wch2b, wcm2b, wcib, wchb, wfcb,
                                    e0, e1, e2, e3, e4);
  }
  cvt_wmo<<<100, cb, 0, stream>>>(Wmo, wmob);

  // A: {new_hidden | mid | ci-part} -- 33x32 = 1056 blocks
  gemmA<<<dim3(33, 32), cb, 0, stream>>>(cmb, wch2b, bch2, wcm2b, bcm2,
                                         wcib, bci, bias,
                                         out_nh, nhb, midb, out_cell /*cif*/);
  // B: {h_proj + fused lc | out} -- 18x32 = 576 blocks
  gemmB<<<dim3(18, 32), cb, 0, stream>>>(nhb, wchb, bch, out_cell /*cif*/,
                                         out_ph, lcb, midb, wmob, bmo, out_out);
  // D: new_cell
  gemmD<<<dim3(16, 32), cb, 0, stream>>>(lcb, wfcb, bfc, out_cell);

  (void)in_sizes; (void)n_in; (void)out_size; (void)ws_size;
}